// Round 3
// baseline (338.197 us; speedup 1.0000x reference)
//
#include <hip/hip_runtime.h>
#include <math.h>

#define Hdim   2048
#define HF4    512
#define Edim   64
#define MARGIN 2e-5f
#define CAPF   16384
#define PROBE0 1237
#define PROBE1 20011

// ws layout (byte offsets)
#define WS_FCNT  0
#define WS_BAD   4
#define WS_PROBE 64            // 128 floats (2 probe tokens x 64 logits)
#define WS_FLIST 1024          // CAPF ints = 64 KB
#define WS_WH    (128*1024)    // 131072 bf16 = 256 KB
#define WS_WL    (384*1024)    // 131072 bf16 = 256 KB
#define WS_NEED  (640*1024)

typedef float f32x4 __attribute__((ext_vector_type(4)));
typedef short bf8   __attribute__((ext_vector_type(8)));

// fp32 -> bf16 hi (truncated) + residual; separate RNE for the lo piece.
__device__ __forceinline__ short bf_hi(float v, float& rem) {
  const unsigned u  = __builtin_bit_cast(unsigned, v);
  const unsigned uh = u & 0xffff0000u;
  rem = v - __builtin_bit_cast(float, uh);
  return (short)(u >> 16);
}
__device__ __forceinline__ short bf_rne(float v) {
  const unsigned u = __builtin_bit_cast(unsigned, v);
  return (short)((u + 0x7fffu + ((u >> 16) & 1u)) >> 16);
}

// ---------------------------------------------------------------------------
// K0: pre-split W into fragment-ordered bf16 hi/lo arrays.
// Frag index f = ((chunk*4 + et)*64 + lane)*8 + j
//   expert e = et*16 + (lane&15);  k = chunk*32 + (lane>>4)*8 + j
// This k-map is BY CONSTRUCTION identical to gate_main's A-fragment loads, so
// the MFMA result is layout-correct for any internal HW k-permutation.
// ---------------------------------------------------------------------------
__global__ __launch_bounds__(256) void gate_prep(
    const float* __restrict__ wgt, short* __restrict__ WH, short* __restrict__ WL)
{
  const int f  = blockIdx.x * 256 + threadIdx.x;   // 0..131071
  const int c  = f >> 11;
  const int et = (f >> 9) & 3;
  const int l  = (f >> 3) & 63;
  const int j  = f & 7;
  const int e  = et * 16 + (l & 15);
  const int k  = c * 32 + (l >> 4) * 8 + j;
  const float w = wgt[(size_t)e * Hdim + k];
  float r; const short h = bf_hi(w, r);
  WH[f] = h; WL[f] = bf_rne(r);
}

// ---------------------------------------------------------------------------
// K1: streaming 4-term split-bf16 MFMA logits + fused softmax/top-9/margin.
// 256 threads = 4 waves; each wave owns 32 tokens x 64 experts. grid = T/128
// = 256 blocks = 1 block/CU. x is streamed once (HBM-bound); W frags from L2.
// ---------------------------------------------------------------------------
__global__ __launch_bounds__(256) void gate_main(
    const float* __restrict__ x, const short* __restrict__ WH,
    const short* __restrict__ WL, const float* __restrict__ eb,
    float* __restrict__ out, int* __restrict__ fcnt, int* __restrict__ flist,
    float* __restrict__ probelg, int T)
{
  __shared__ float lg[4][32][68];
  const int t  = threadIdx.x;
  const int wv = t >> 6;
  const int ln = t & 63;
  const int tb = blockIdx.x * 128 + wv * 32;

  const float* xp0 = x + (size_t)(tb + (ln & 15)) * Hdim + (ln >> 4) * 8;
  const float* xp1 = xp0 + (size_t)16 * Hdim;

  f32x4 acc[2][4];
  #pragma unroll
  for (int i = 0; i < 2; ++i)
    #pragma unroll
    for (int j = 0; j < 4; ++j) acc[i][j] = (f32x4)0.f;

  f32x4 A0[2][2], A1[2][2];
  bf8 B0h[4], B0l[4], B1h[4], B1l[4];

  auto LOADA = [&](f32x4 (&A)[2][2], int ks) {
    const int ko = ks * 32;
    A[0][0] = *(const f32x4*)(xp0 + ko);  A[0][1] = *(const f32x4*)(xp0 + ko + 4);
    A[1][0] = *(const f32x4*)(xp1 + ko);  A[1][1] = *(const f32x4*)(xp1 + ko + 4);
  };
  auto LOADB = [&](bf8 (&Bh)[4], bf8 (&Bl)[4], int ks) {
    #pragma unroll
    for (int et = 0; et < 4; ++et) {
      const size_t idx = ((size_t)(ks * 4 + et) * 64 + ln) * 8;
      Bh[et] = *(const bf8*)(WH + idx);
      Bl[et] = *(const bf8*)(WL + idx);
    }
  };
  auto COMPUTE = [&](const f32x4 (&A)[2][2], const bf8 (&Bh)[4], const bf8 (&Bl)[4]) {
    bf8 ah[2], al[2];
    #pragma unroll
    for (int tt = 0; tt < 2; ++tt)
      #pragma unroll
      for (int j = 0; j < 4; ++j) {
        float r;
        ah[tt][j]     = bf_hi(A[tt][0][j], r);  al[tt][j]     = bf_rne(r);
        ah[tt][j + 4] = bf_hi(A[tt][1][j], r);  al[tt][j + 4] = bf_rne(r);
      }
    #pragma unroll
    for (int et = 0; et < 4; ++et)
      #pragma unroll
      for (int tt = 0; tt < 2; ++tt) {
        acc[tt][et] = __builtin_amdgcn_mfma_f32_16x16x32_bf16(ah[tt], Bh[et], acc[tt][et], 0, 0, 0);
        acc[tt][et] = __builtin_amdgcn_mfma_f32_16x16x32_bf16(ah[tt], Bl[et], acc[tt][et], 0, 0, 0);
        acc[tt][et] = __builtin_amdgcn_mfma_f32_16x16x32_bf16(al[tt], Bh[et], acc[tt][et], 0, 0, 0);
        acc[tt][et] = __builtin_amdgcn_mfma_f32_16x16x32_bf16(al[tt], Bl[et], acc[tt][et], 0, 0, 0);
      }
  };

  LOADA(A0, 0); LOADB(B0h, B0l, 0);
  for (int ks = 0; ks < 64; ks += 2) {
    LOADA(A1, ks + 1); LOADB(B1h, B1l, ks + 1);
    COMPUTE(A0, B0h, B0l);
    if (ks + 2 < 64) { LOADA(A0, ks + 2); LOADB(B0h, B0l, ks + 2); }
    COMPUTE(A1, B1h, B1l);
  }

  // ---- accumulators -> logits LDS (C/D: col=lane&15, row=(lane>>4)*4+reg) ----
  const int cg = ln >> 4, ce = ln & 15;
  #pragma unroll
  for (int tt = 0; tt < 2; ++tt)
    #pragma unroll
    for (int et = 0; et < 4; ++et)
      #pragma unroll
      for (int r = 0; r < 4; ++r)
        lg[wv][tt * 16 + cg * 4 + r][et * 16 + ce] = acc[tt][et][r];
  __syncthreads();

  // ---- per-token softmax + top-9 + margin flag (wave per token set) ----
  const float bias = eb[ln];
  for (int s = 0; s < 32; ++s) {
    const int gt = tb + s;
    const float z = lg[wv][s][ln];
    if (gt == PROBE0) probelg[ln] = z;
    if (gt == PROBE1) probelg[64 + ln] = z;
    float mx = z;
    #pragma unroll
    for (int off = 32; off; off >>= 1) mx = fmaxf(mx, __shfl_xor(mx, off, 64));
    const float p = expf(z - mx);
    float Zs = p;
    #pragma unroll
    for (int off = 32; off; off >>= 1) Zs += __shfl_xor(Zs, off, 64);
    const float sco = p / Zs;
    float bsw = sco + bias;
    float prev = 0.f, gmin = 1e30f, mys = 0.f;
    int myi = 0;
    #pragma unroll
    for (int r = 0; r < 9; ++r) {
      float v = bsw;
      int idx = ln;
      #pragma unroll
      for (int off = 32; off; off >>= 1) {       // argmax, ties -> lower index
        const float ov = __shfl_xor(v, off, 64);
        const int   oi = __shfl_xor(idx, off, 64);
        if (ov > v || (ov == v && oi < idx)) { v = ov; idx = oi; }
      }
      if (r) gmin = fminf(gmin, prev - v);
      prev = v;
      if (r < 8) {
        const float sv = __shfl(sco, idx, 64);
        if (ln == r)  { myi = idx; mys = sv; }
        if (ln == idx) bsw = -1e30f;
      }
    }
    float wsum = (ln < 8) ? mys : 0.f;
    #pragma unroll
    for (int off = 32; off; off >>= 1) wsum += __shfl_xor(wsum, off, 64);
    if (ln < 8) {
      out[(size_t)gt * 8 + ln] = (float)myi;                    // indices as float
      out[(size_t)T * 8 + (size_t)gt * 8 + ln] = mys / (wsum + 1e-20f);
    }
    if (ln == 0 && gmin < MARGIN) {
      const int pos = atomicAdd(fcnt, 1);
      if (pos < CAPF) flist[pos] = gt;
    }
  }
}

// ---------------------------------------------------------------------------
// K2: structural self-check. fp32-VALU recompute of 2 probe tokens' logits;
// >0.05 discrepancy (split noise is <1e-3) or flist overflow => allbad.
// ---------------------------------------------------------------------------
__global__ __launch_bounds__(128) void gate_check(
    const float* __restrict__ x, const float* __restrict__ wgt,
    const float* __restrict__ probelg, const int* __restrict__ fcnt,
    int* __restrict__ allbad)
{
  const int wv = threadIdx.x >> 6, ln = threadIdx.x & 63;
  const int P = wv ? PROBE1 : PROBE0;
  const float* xr = x + (size_t)P * Hdim;
  const float* wr = wgt + (size_t)ln * Hdim;
  float a0 = 0.f, a1 = 0.f, a2 = 0.f, a3 = 0.f;
  for (int k = 0; k < Hdim; k += 4) {
    a0 = fmaf(xr[k],     wr[k],     a0);
    a1 = fmaf(xr[k + 1], wr[k + 1], a1);
    a2 = fmaf(xr[k + 2], wr[k + 2], a2);
    a3 = fmaf(xr[k + 3], wr[k + 3], a3);
  }
  const float z = (a0 + a1) + (a2 + a3);
  if (fabsf(z - probelg[wv * 64 + ln]) > 0.05f) *allbad = 1;
  if (threadIdx.x == 0 && *fcnt > CAPF) *allbad = 1;
}

// ---------------------------------------------------------------------------
// K3: fp64 fixup. Normal mode: flagged near-tie tokens. allbad mode: ALL
// tokens (correct-but-slow fallback if the MFMA path is structurally off).
// ---------------------------------------------------------------------------
__global__ __launch_bounds__(256) void gate_fix(
    const float* __restrict__ x, const float* __restrict__ wgt,
    const float* __restrict__ eb, float* __restrict__ out,
    const int* __restrict__ fcnt, const int* __restrict__ flist,
    const int* __restrict__ allbad, int T)
{
  __shared__ float4 xl[4 * HF4];           // 32 KB
  __shared__ double part[4][64][4];        // 8 KB
  __shared__ int tks[4];
  const int bad = *allbad;
  int n = bad ? T : *fcnt;
  if (n <= 0) return;
  if (!bad && n > CAPF) n = CAPF;
  const int nb = (n + 3) >> 2;
  const int t = threadIdx.x;
  for (int b = blockIdx.x; b < nb; b += gridDim.x) {
    if (t < 4) {
      const int li = b * 4 + t;
      const int ci = li < n ? li : n - 1;      // clamp: benign duplicate work
      tks[t] = bad ? ci : flist[ci];
    }
    __syncthreads();
    {
      const int m = t >> 6, l2 = t & 63;
      const float4* src = (const float4*)x + (size_t)tks[m] * HF4;
      #pragma unroll
      for (int ii = 0; ii < 8; ++ii) xl[m * HF4 + ii * 64 + l2] = src[ii * 64 + l2];
    }
    __syncthreads();
    const int e = t >> 2, q = t & 3;          // 64 experts x 4 k-quarters
    double acc[4] = {0.0, 0.0, 0.0, 0.0};
    const float4* w4 = (const float4*)wgt + (size_t)e * HF4;
    for (int c = 0; c < 128; ++c) {
      const int f4 = c * 4 + q;
      const float4 wvv = w4[f4];
      #pragma unroll
      for (int m = 0; m < 4; ++m) {
        const float4 xv = xl[m * HF4 + f4];
        acc[m] += (double)xv.x * (double)wvv.x + (double)xv.y * (double)wvv.y
                + (double)xv.z * (double)wvv.z + (double)xv.w * (double)wvv.w;
      }
    }
    #pragma unroll
    for (int m = 0; m < 4; ++m) part[m][e][q] = acc[m];
    __syncthreads();
    {
      const int m = t >> 6, ln = t & 63;      // wave m -> token m, lane = expert
      const double z = part[m][ln][0] + part[m][ln][1] + part[m][ln][2] + part[m][ln][3];
      double mx = z;
      #pragma unroll
      for (int off = 32; off; off >>= 1) mx = fmax(mx, __shfl_xor(mx, off, 64));
      const double p = exp(z - mx);
      double Zs = p;
      #pragma unroll
      for (int off = 32; off; off >>= 1) Zs += __shfl_xor(Zs, off, 64);
      const double sco = p / Zs;
      double bsw = sco + (double)eb[ln];
      double mys = 0.0;
      int myi = 0;
      #pragma unroll
      for (int r = 0; r < 8; ++r) {
        double v = bsw;
        int idx = ln;
        #pragma unroll
        for (int off = 32; off; off >>= 1) {
          const double ov = __shfl_xor(v, off, 64);
          const int   oi = __shfl_xor(idx, off, 64);
          if (ov > v || (ov == v && oi < idx)) { v = ov; idx = oi; }
        }
        const double sv = __shfl(sco, idx, 64);
        if (ln == r)  { myi = idx; mys = sv; }
        if (ln == idx) bsw = -1.0e300;
      }
      double wsum = (ln < 8) ? mys : 0.0;
      #pragma unroll
      for (int off = 32; off; off >>= 1) wsum += __shfl_xor(wsum, off, 64);
      const int gt = tks[m];
      if (ln < 8) {
        out[(size_t)gt * 8 + ln] = (float)myi;
        out[(size_t)T * 8 + (size_t)gt * 8 + ln] = (float)(mys / (wsum + 1e-20));
      }
    }
    __syncthreads();
  }
}

extern "C" void kernel_launch(void* const* d_in, const int* in_sizes, int n_in,
                              void* d_out, int out_size, void* d_ws, size_t ws_size,
                              hipStream_t stream) {
  const float* x   = (const float*)d_in[0];
  const float* wgt = (const float*)d_in[1];
  const float* eb  = (const float*)d_in[2];
  float* out = (float*)d_out;
  const int T = in_sizes[0] / Hdim;          // 32768
  char* ws = (char*)d_ws;
  int*   fcnt    = (int*)(ws + WS_FCNT);
  int*   bad     = (int*)(ws + WS_BAD);
  float* probelg = (float*)(ws + WS_PROBE);
  int*   flist   = (int*)(ws + WS_FLIST);
  short* WH      = (short*)(ws + WS_WH);
  short* WL      = (short*)(ws + WS_WL);

  if (ws_size < WS_NEED) {                   // tiny-ws fallback: full fp64 path
    hipMemsetAsync(ws, 0, 8, stream);
    hipMemsetAsync(ws + WS_BAD, 1, 1, stream);   // allbad != 0
    hipLaunchKernelGGL(gate_fix, dim3(256), dim3(256), 0, stream,
                       x, wgt, eb, out, fcnt, flist, bad, T);
    return;
  }
  hipMemsetAsync(ws, 0, 8, stream);          // fcnt = 0, allbad = 0
  hipLaunchKernelGGL(gate_prep, dim3(512), dim3(256), 0, stream, wgt, WH, WL);
  hipLaunchKernelGGL(gate_main, dim3(T / 128), dim3(256), 0, stream,
                     x, WH, WL, eb, out, fcnt, flist, probelg, T);
  hipLaunchKernelGGL(gate_check, dim3(1), dim3(128), 0, stream,
                     x, wgt, probelg, fcnt, bad);
  hipLaunchKernelGGL(gate_fix, dim3(256), dim3(256), 0, stream,
                     x, wgt, eb, out, fcnt, flist, bad, T);
}

// Round 4
// 226.700 us; speedup vs baseline: 1.4918x; 1.4918x over previous
//
#include <hip/hip_runtime.h>
#include <math.h>

#define Hdim   2048
#define HF4    512
#define MARGIN 2e-5f
#define CAPF   16384
#define PROBE0 1237
#define PROBE1 20011

// ws layout (byte offsets)
#define WS_FCNT  0
#define WS_BAD   4
#define WS_PROBE 64            // 128 floats (2 probe tokens x 64 logits)
#define WS_FLIST 1024          // CAPF ints = 64 KB
#define WS_WH    (128*1024)    // 131072 bf16 = 256 KB
#define WS_WL    (384*1024)    // 131072 bf16 = 256 KB
#define WS_NEED  (640*1024)

typedef float f32x4 __attribute__((ext_vector_type(4)));
typedef short bf8   __attribute__((ext_vector_type(8)));

typedef const __attribute__((address_space(1))) unsigned int ga_u32;
typedef __attribute__((address_space(3))) unsigned int la_u32;
__device__ __forceinline__ void gload16(const void* g, void* l) {
  __builtin_amdgcn_global_load_lds((ga_u32*)g, (la_u32*)l, 16, 0, 0);
}

// fp32 -> bf16 hi (truncated) + exact residual; RNE for the lo piece.
__device__ __forceinline__ short bf_hi(float v, float& rem) {
  const unsigned u  = __builtin_bit_cast(unsigned, v);
  const unsigned uh = u & 0xffff0000u;
  rem = v - __builtin_bit_cast(float, uh);
  return (short)(u >> 16);
}
__device__ __forceinline__ short bf_rne(float v) {
  const unsigned u = __builtin_bit_cast(unsigned, v);
  return (short)((u + 0x7fffu + ((u >> 16) & 1u)) >> 16);
}

// ---------------------------------------------------------------------------
// K0: pre-split W into fragment-ordered bf16 hi/lo arrays (same as round 3).
// f = ((ks*4 + et)*64 + lane)*8 + j ; e = et*16+(lane&15); k = ks*32+(lane>>4)*8+j
// ---------------------------------------------------------------------------
__global__ __launch_bounds__(256) void gate_prep(
    const float* __restrict__ wgt, short* __restrict__ WH, short* __restrict__ WL)
{
  const int f  = blockIdx.x * 256 + threadIdx.x;   // 0..131071
  const int c  = f >> 11;
  const int et = (f >> 9) & 3;
  const int l  = (f >> 3) & 63;
  const int j  = f & 7;
  const int e  = et * 16 + (l & 15);
  const int k  = c * 32 + (l >> 4) * 8 + j;
  const float w = wgt[(size_t)e * Hdim + k];
  float r; const short h = bf_hi(w, r);
  WH[f] = h; WL[f] = bf_rne(r);
}

// ---------------------------------------------------------------------------
// K1: HBM-paced 4-term split-bf16 MFMA gate.
// 256 thr = 4 waves; wave = 16 tokens x 64 experts; block = 64 tokens.
// Grid T/64 = 512 -> 2 blocks/CU. W-chunks staged to LDS (dbuf, 16 KB) via
// global_load_lds and shared by all 4 waves; x loaded direct, depth-2 regs.
// ---------------------------------------------------------------------------
__global__ __launch_bounds__(256, 2) void gate_main(
    const float* __restrict__ x, const short* __restrict__ WH,
    const short* __restrict__ WL, const float* __restrict__ eb,
    float* __restrict__ out, int* __restrict__ fcnt, int* __restrict__ flist,
    float* __restrict__ probelg, int T)
{
  __shared__ __align__(16) short wlds0[4096];   // [hi 2048 | lo 2048]
  __shared__ __align__(16) short wlds1[4096];
  __shared__ float lg[4][16][68];
  const int t  = threadIdx.x;
  const int wv = t >> 6;
  const int ln = t & 63;
  const int tb = blockIdx.x * 64 + wv * 16;

  const float* xp = x + (size_t)(tb + (ln & 15)) * Hdim + (ln >> 4) * 8;

  f32x4 acc[4];
  #pragma unroll
  for (int et = 0; et < 4; ++et) acc[et] = (f32x4)0.f;

  f32x4 A0[2], A1[2];                    // static names: no dynamic indexing

  // one k-step: read B frags from bufc, split A, stage next W, prefetch x,
  // 16 MFMA, barrier.  Ac is consumed then refilled with k-step ks+2.
  auto ITER = [&](f32x4 (&Ac)[2], int ks, const short* bufc, short* bufn) {
    bf8 Bh[4], Bl[4];
    #pragma unroll
    for (int et = 0; et < 4; ++et) {     // ds_read_b128 x8, contiguous
      Bh[et] = *(const bf8*)&bufc[(et * 64 + ln) * 8];
      Bl[et] = *(const bf8*)&bufc[2048 + (et * 64 + ln) * 8];
    }
    bf8 ah, al;
    #pragma unroll
    for (int j = 0; j < 4; ++j) {
      float r;
      ah[j]     = bf_hi(Ac[0][j], r);  al[j]     = bf_rne(r);
      ah[j + 4] = bf_hi(Ac[1][j], r);  al[j + 4] = bf_rne(r);
    }
    if (ks + 1 < 64) {                   // stage W chunk ks+1 into bufn
      gload16(WH + (size_t)(ks + 1) * 2048 + t * 8, bufn + t * 8);
      gload16(WL + (size_t)(ks + 1) * 2048 + t * 8, bufn + 2048 + t * 8);
    }
    if (ks + 2 < 64) {                   // refill Ac with x for k-step ks+2
      Ac[0] = *(const f32x4*)(xp + (ks + 2) * 32);
      Ac[1] = *(const f32x4*)(xp + (ks + 2) * 32 + 4);
    }
    #pragma unroll
    for (int et = 0; et < 4; ++et) {
      acc[et] = __builtin_amdgcn_mfma_f32_16x16x32_bf16(ah, Bh[et], acc[et], 0, 0, 0);
      acc[et] = __builtin_amdgcn_mfma_f32_16x16x32_bf16(ah, Bl[et], acc[et], 0, 0, 0);
      acc[et] = __builtin_amdgcn_mfma_f32_16x16x32_bf16(al, Bh[et], acc[et], 0, 0, 0);
      acc[et] = __builtin_amdgcn_mfma_f32_16x16x32_bf16(al, Bl[et], acc[et], 0, 0, 0);
    }
    __syncthreads();
  };

  // prologue: stage W(0), load x for ks 0 and 1
  gload16(WH + t * 8, wlds0 + t * 8);
  gload16(WL + t * 8, wlds0 + 2048 + t * 8);
  A0[0] = *(const f32x4*)(xp);       A0[1] = *(const f32x4*)(xp + 4);
  A1[0] = *(const f32x4*)(xp + 32);  A1[1] = *(const f32x4*)(xp + 36);
  __syncthreads();

  for (int ks = 0; ks < 64; ks += 2) {
    ITER(A0, ks,     wlds0, wlds1);
    ITER(A1, ks + 1, wlds1, wlds0);
  }

  // ---- accumulators -> logits LDS (C/D: col=lane&15, row=(lane>>4)*4+reg) ----
  const int cg = ln >> 4, ce = ln & 15;
  #pragma unroll
  for (int et = 0; et < 4; ++et)
    #pragma unroll
    for (int r = 0; r < 4; ++r)
      lg[wv][cg * 4 + r][et * 16 + ce] = acc[et][r];
  __syncthreads();

  // ---- per-token softmax + top-9 + margin flag (wave per its 16 tokens) ----
  const float bias = eb[ln];
  for (int s = 0; s < 16; ++s) {
    const int gt = tb + s;
    const float z = lg[wv][s][ln];
    if (gt == PROBE0) probelg[ln] = z;
    if (gt == PROBE1) probelg[64 + ln] = z;
    float mx = z;
    #pragma unroll
    for (int off = 32; off; off >>= 1) mx = fmaxf(mx, __shfl_xor(mx, off, 64));
    const float p = expf(z - mx);
    float Zs = p;
    #pragma unroll
    for (int off = 32; off; off >>= 1) Zs += __shfl_xor(Zs, off, 64);
    const float sco = p / Zs;
    float bsw = sco + bias;
    float prev = 0.f, gmin = 1e30f, mys = 0.f;
    int myi = 0;
    #pragma unroll
    for (int r = 0; r < 9; ++r) {
      float v = bsw;
      int idx = ln;
      #pragma unroll
      for (int off = 32; off; off >>= 1) {       // argmax, ties -> lower index
        const float ov = __shfl_xor(v, off, 64);
        const int   oi = __shfl_xor(idx, off, 64);
        if (ov > v || (ov == v && oi < idx)) { v = ov; idx = oi; }
      }
      if (r) gmin = fminf(gmin, prev - v);
      prev = v;
      if (r < 8) {
        const float sv = __shfl(sco, idx, 64);
        if (ln == r)  { myi = idx; mys = sv; }
        if (ln == idx) bsw = -1e30f;
      }
    }
    float wsum = (ln < 8) ? mys : 0.f;
    #pragma unroll
    for (int off = 32; off; off >>= 1) wsum += __shfl_xor(wsum, off, 64);
    if (ln < 8) {
      out[(size_t)gt * 8 + ln] = (float)myi;                    // indices as float
      out[(size_t)T * 8 + (size_t)gt * 8 + ln] = mys / (wsum + 1e-20f);
    }
    if (ln == 0 && gmin < MARGIN) {
      const int pos = atomicAdd(fcnt, 1);
      if (pos < CAPF) flist[pos] = gt;
    }
  }
}

// ---------------------------------------------------------------------------
// K2: structural self-check (parallelized): 2 blocks x 256 thr, each block
// recomputes one probe token's 64 logits in fp32 VALU (vectorized).
// ---------------------------------------------------------------------------
__global__ __launch_bounds__(256) void gate_check(
    const float* __restrict__ x, const float* __restrict__ wgt,
    const float* __restrict__ probelg, const int* __restrict__ fcnt,
    int* __restrict__ allbad)
{
  __shared__ float part[64][4];
  const int p = blockIdx.x;
  const int P = p ? PROBE1 : PROBE0;
  const int t = threadIdx.x, e = t >> 2, q = t & 3;
  const float4* xr = (const float4*)(x + (size_t)P * Hdim);
  const float4* wr = (const float4*)(wgt + (size_t)e * Hdim);
  float a = 0.f, b = 0.f, c = 0.f, d = 0.f;
  for (int i = 0; i < 128; ++i) {
    const int f4 = i * 4 + q;
    const float4 xv = xr[f4], wv = wr[f4];
    a = fmaf(xv.x, wv.x, a); b = fmaf(xv.y, wv.y, b);
    c = fmaf(xv.z, wv.z, c); d = fmaf(xv.w, wv.w, d);
  }
  part[e][q] = (a + b) + (c + d);
  __syncthreads();
  if (q == 0) {
    const float z = part[e][0] + part[e][1] + part[e][2] + part[e][3];
    if (fabsf(z - probelg[p * 64 + e]) > 0.05f) *allbad = 1;
  }
  if (t == 0 && p == 0 && *fcnt > CAPF) *allbad = 1;
}

// ---------------------------------------------------------------------------
// K3: fp64 fixup. Normal: flagged near-tie tokens. allbad: ALL tokens.
// ---------------------------------------------------------------------------
__global__ __launch_bounds__(256) void gate_fix(
    const float* __restrict__ x, const float* __restrict__ wgt,
    const float* __restrict__ eb, float* __restrict__ out,
    const int* __restrict__ fcnt, const int* __restrict__ flist,
    const int* __restrict__ allbad, int T)
{
  __shared__ float4 xl[4 * HF4];           // 32 KB
  __shared__ double part[4][64][4];        // 8 KB
  __shared__ int tks[4];
  const int bad = *allbad;
  int n = bad ? T : *fcnt;
  if (n <= 0) return;
  if (!bad && n > CAPF) n = CAPF;
  const int nb = (n + 3) >> 2;
  const int t = threadIdx.x;
  for (int b = blockIdx.x; b < nb; b += gridDim.x) {
    if (t < 4) {
      const int li = b * 4 + t;
      const int ci = li < n ? li : n - 1;      // clamp: benign duplicate work
      tks[t] = bad ? ci : flist[ci];
    }
    __syncthreads();
    {
      const int m = t >> 6, l2 = t & 63;
      const float4* src = (const float4*)x + (size_t)tks[m] * HF4;
      #pragma unroll
      for (int ii = 0; ii < 8; ++ii) xl[m * HF4 + ii * 64 + l2] = src[ii * 64 + l2];
    }
    __syncthreads();
    const int e = t >> 2, q = t & 3;          // 64 experts x 4 k-quarters
    double acc[4] = {0.0, 0.0, 0.0, 0.0};
    const float4* w4 = (const float4*)wgt + (size_t)e * HF4;
    for (int c = 0; c < 128; ++c) {
      const int f4 = c * 4 + q;
      const float4 wvv = w4[f4];
      #pragma unroll
      for (int m = 0; m < 4; ++m) {
        const float4 xv = xl[m * HF4 + f4];
        acc[m] += (double)xv.x * (double)wvv.x + (double)xv.y * (double)wvv.y
                + (double)xv.z * (double)wvv.z + (double)xv.w * (double)wvv.w;
      }
    }
    #pragma unroll
    for (int m = 0; m < 4; ++m) part[m][e][q] = acc[m];
    __syncthreads();
    {
      const int m = t >> 6, ln = t & 63;      // wave m -> token m, lane = expert
      const double z = part[m][ln][0] + part[m][ln][1] + part[m][ln][2] + part[m][ln][3];
      double mx = z;
      #pragma unroll
      for (int off = 32; off; off >>= 1) mx = fmax(mx, __shfl_xor(mx, off, 64));
      const double p = exp(z - mx);
      double Zs = p;
      #pragma unroll
      for (int off = 32; off; off >>= 1) Zs += __shfl_xor(Zs, off, 64);
      const double sco = p / Zs;
      double bsw = sco + (double)eb[ln];
      double mys = 0.0;
      int myi = 0;
      #pragma unroll
      for (int r = 0; r < 8; ++r) {
        double v = bsw;
        int idx = ln;
        #pragma unroll
        for (int off = 32; off; off >>= 1) {
          const double ov = __shfl_xor(v, off, 64);
          const int   oi = __shfl_xor(idx, off, 64);
          if (ov > v || (ov == v && oi < idx)) { v = ov; idx = oi; }
        }
        const double sv = __shfl(sco, idx, 64);
        if (ln == r)  { myi = idx; mys = sv; }
        if (ln == idx) bsw = -1.0e300;
      }
      double wsum = (ln < 8) ? mys : 0.0;
      #pragma unroll
      for (int off = 32; off; off >>= 1) wsum += __shfl_xor(wsum, off, 64);
      const int gt = tks[m];
      if (ln < 8) {
        out[(size_t)gt * 8 + ln] = (float)myi;
        out[(size_t)T * 8 + (size_t)gt * 8 + ln] = (float)(mys / (wsum + 1e-20));
      }
    }
    __syncthreads();
  }
}

extern "C" void kernel_launch(void* const* d_in, const int* in_sizes, int n_in,
                              void* d_out, int out_size, void* d_ws, size_t ws_size,
                              hipStream_t stream) {
  const float* x   = (const float*)d_in[0];
  const float* wgt = (const float*)d_in[1];
  const float* eb  = (const float*)d_in[2];
  float* out = (float*)d_out;
  const int T = in_sizes[0] / Hdim;          // 32768
  char* ws = (char*)d_ws;
  int*   fcnt    = (int*)(ws + WS_FCNT);
  int*   bad     = (int*)(ws + WS_BAD);
  float* probelg = (float*)(ws + WS_PROBE);
  int*   flist   = (int*)(ws + WS_FLIST);
  short* WH      = (short*)(ws + WS_WH);
  short* WL      = (short*)(ws + WS_WL);

  if (ws_size < WS_NEED) {                   // tiny-ws fallback: full fp64 path
    hipMemsetAsync(ws, 0, 8, stream);
    hipMemsetAsync(ws + WS_BAD, 1, 1, stream);   // allbad != 0
    hipLaunchKernelGGL(gate_fix, dim3(256), dim3(256), 0, stream,
                       x, wgt, eb, out, fcnt, flist, bad, T);
    return;
  }
  hipMemsetAsync(ws, 0, 8, stream);          // fcnt = 0, allbad = 0
  hipLaunchKernelGGL(gate_prep, dim3(512), dim3(256), 0, stream, wgt, WH, WL);
  hipLaunchKernelGGL(gate_main, dim3(T / 64), dim3(256), 0, stream,
                     x, WH, WL, eb, out, fcnt, flist, probelg, T);
  hipLaunchKernelGGL(gate_check, dim3(2), dim3(256), 0, stream,
                     x, wgt, probelg, fcnt, bad);
  hipLaunchKernelGGL(gate_fix, dim3(256), dim3(256), 0, stream,
                     x, wgt, eb, out, fcnt, flist, bad, T);
}